// Round 9
// baseline (92.205 us; speedup 1.0000x reference)
//
#include <hip/hip_runtime.h>

// Problem constants (from reference setup_inputs)
static constexpr int B_ = 2, N_ = 2048, NL_ = 512, IN_C_ = 16, C_ = 32, H_ = 32;
static constexpr float R1SQ = (float)(0.07 * 0.07);   // (RADIUS*1)^2
static constexpr float R2SQ = (float)(0.14 * 0.14);   // (RADIUS*2)^2

typedef __attribute__((ext_vector_type(8))) short bf16x8;  // 8 bf16 = 4 VGPRs
typedef __attribute__((ext_vector_type(4))) float f32x4;   // 4 fp32 acc

// jax.nn.gelu(approximate=True) via 0.5x(1+tanh(z)) = x*(1 - 1/(exp(2z)+1)),
// log2e folded: exp(2z) = exp2(2.3022082*x*(1+0.044715x^2)).
__device__ __forceinline__ float gelu_tanh(float x) {
    float z2 = 2.3022082f * x * fmaf(0.044715f * x, x, 1.0f);
    float e = __builtin_amdgcn_exp2f(z2);
    float t = __builtin_amdgcn_rcpf(e + 1.0f);
    return x - x * t;
}

// fp32 -> bf16 bits, round-to-nearest-even (inputs finite)
__device__ __forceinline__ short f2bf(float x) {
    unsigned u = __float_as_uint(x);
    u += 0x7fffu + ((u >> 16) & 1u);
    return (short)(u >> 16);
}

// f = pndata @ W_lift + b_lift   (B*N rows of 16 -> 32)
__global__ __launch_bounds__(256)
void lift_kernel(const float* __restrict__ pnd,
                 const float* __restrict__ Wl, const float* __restrict__ bl,
                 float* __restrict__ f)
{
    __shared__ float sW[IN_C_ * C_];
    __shared__ float sb[C_];
    int tid = threadIdx.x;
    for (int idx = tid; idx < IN_C_ * C_; idx += 256) sW[idx] = Wl[idx];
    if (tid < C_) sb[tid] = bl[tid];
    __syncthreads();
    int c = tid & 31;
    int row = blockIdx.x * 8 + (tid >> 5);
    if (row >= B_ * N_) return;
    const float* p = pnd + (size_t)row * IN_C_;
    float s = sb[c];
#pragma unroll
    for (int m = 0; m < IN_C_; ++m) s = fmaf(p[m], sW[m * C_ + c], s);
    f[(size_t)row * C_ + c] = s;
}

// One block per (b, latent token i). 512 threads = 8 waves.
// Each wave scans a 256-point segment (4 ballot rounds) and runs ~1
// 16-entry MFMA tile. Zero block barriers in Pass B. launch_bounds(512,8)
// caps VGPR at 64 so 4 blocks/CU (= 32 waves/CU) stay co-resident.
__global__ __launch_bounds__(512, 8)
void magno_mfma(const float* __restrict__ x_coord,   // (B,N,2)
                const float* __restrict__ lat,        // (NL,2)
                const float* __restrict__ kW1, const float* __restrict__ kb1,
                const float* __restrict__ kW2, const float* __restrict__ kb2,
                const float* __restrict__ kW3, const float* __restrict__ kb3,
                const float* __restrict__ f,          // (B,N,32) fp32
                float* __restrict__ out)              // (B,NL,32)
{
    __shared__ float sW23[2][H_ * H_];                  // staged kW2, kW3
    __shared__ __align__(16) float sW1i[H_][4];         // interleaved {r0, r1, a1, pad} per k
    __shared__ unsigned jlist[8][256];                  // per-wave segments
    __shared__ __align__(16) short strans[8][16 * 40];  // per-wave bf16 transpose, pitch 40
    __shared__ float sred[8][C_];
    __shared__ int scnt[8][2];                          // per-wave {n, c1}

    const int tid  = threadIdx.x;
    const int lane = tid & 63;
    const int wid  = tid >> 6;     // 0..7
    const int qd   = lane >> 4;    // quad 0..3
    const int li   = lane & 15;
    const int bi = blockIdx.x;
    const int b = bi >> 9, i = bi & (NL_ - 1);
    const float xq0 = lat[2 * i], xq1 = lat[2 * i + 1];

    // ---- stage W2/W3 coalesced; W1 interleaved for b128 reads in the loop ----
    for (int idx = tid; idx < H_ * H_; idx += 512) {
        sW23[0][idx] = kW2[idx];
        sW23[1][idx] = kW3[idx];
    }
    if (tid < H_) {
        sW1i[tid][0] = kW1[tid];            // row 0 (y0)
        sW1i[tid][1] = kW1[H_ + tid];       // row 1 (y1)
        // fold xq-dependent part + bias
        sW1i[tid][2] = fmaf(xq0, kW1[2 * H_ + tid], fmaf(xq1, kW1[3 * H_ + tid], kb1[tid]));
        sW1i[tid][3] = 0.0f;
    }
    const float b2A = kb2[li], b2B = kb2[li + 16];
    const float b3A = kb3[li], b3B = kb3[li + 16];

    // ---- Pass A: wave-private ballot compaction over j in [256*wid, 256*(wid+1)) ----
    const float2* __restrict__ xc = (const float2*)(x_coord + (size_t)b * N_ * 2);
    const unsigned long long ltmask = (1ull << lane) - 1ull;
    float2 ys[4];
#pragma unroll
    for (int t = 0; t < 4; ++t) ys[t] = xc[256 * wid + 64 * t + lane];   // all in flight
    int cnt = 0, c1w = 0;
#pragma unroll
    for (int t = 0; t < 4; ++t) {
        float dy0 = ys[t].x - xq0, dy1 = ys[t].y - xq1;
        float d2 = dy0 * dy0 + dy1 * dy1;
        bool in2 = d2 <= R2SQ;
        bool in1 = d2 <= R1SQ;
        unsigned long long m2 = __ballot(in2);
        unsigned long long m1 = __ballot(in1);
        if (in2) {
            int pos = cnt + __popcll(m2 & ltmask);
            jlist[wid][pos] = (unsigned)(256 * wid + 64 * t + lane) | (in1 ? 0x80000000u : 0u);
        }
        cnt += __popcll(m2);   // wave-uniform
        c1w += __popcll(m1);
    }
    if (lane == 0) { scnt[wid][0] = cnt; scnt[wid][1] = c1w; }
    __syncthreads();   // covers weight staging + scnt publication

    int n = 0, c1 = 0;
#pragma unroll
    for (int w = 0; w < 8; ++w) { n += scnt[w][0]; c1 += scnt[w][1]; }
    const float inv2 = 1.0f / (float)(n  > 0 ? n  : 1);
    const float inv1 = 1.0f / (float)(c1 > 0 ? c1 : 1);

    // ---- B-fragments from LDS (verified 16x16x32 layout): B[k=qd*8+jj][n=li+16*nt] ----
    bf16x8 w2f[2], w3f[2];
#pragma unroll
    for (int nt = 0; nt < 2; ++nt) {
        int n0 = li + 16 * nt;
#pragma unroll
        for (int jj = 0; jj < 8; ++jj) {
            int k = qd * 8 + jj;
            w2f[nt][jj] = f2bf(sW23[0][k * H_ + n0]);
            w3f[nt][jj] = f2bf(sW23[1][k * H_ + n0]);
        }
    }

    short* tb = &strans[wid][0];
    const unsigned* __restrict__ jl = &jlist[wid][0];
    const float* __restrict__ fbase = f + (size_t)b * N_ * C_;

    float accA = 0.0f, accB = 0.0f;   // channels li and li+16

    // ---- Pass B: one 16-entry tile per iteration, wave-private, no block barriers ----
    for (int base = 0; base < cnt; base += 16) {
        // f prefetch for epilogue entries el = base + 4*qd + r (hidden under MLP)
        unsigned pks[4];
        float fAv[4], fBv[4];
#pragma unroll
        for (int r = 0; r < 4; ++r) {
            int el = base + 4 * qd + r;
            pks[r] = jl[el & 255];               // safe index; w=0 masks padding
            int j = (int)(pks[r] & (unsigned)(N_ - 1));
            const float* fr = fbase + (size_t)j * C_;
            fAv[r] = fr[li];
            fBv[r] = fr[li + 16];
        }

        // layer 1 directly in A-fragment layout: entry m = base + li
        int jm = (int)(jl[(base + li) & 255] & (unsigned)(N_ - 1));
        float2 y = xc[jm];   // L1/L2-warm (Pass A read all of xc)
        bf16x8 hfrag;
#pragma unroll
        for (int jj = 0; jj < 8; ++jj) {
            int k = qd * 8 + jj;
            float4 wv = *(const float4*)&sW1i[k][0];   // one b128 per k
            hfrag[jj] = f2bf(gelu_tanh(fmaf(y.x, wv.x, fmaf(y.y, wv.y, wv.z))));
        }

        // layer 2 mfma
        f32x4 z = {0.f, 0.f, 0.f, 0.f};
        f32x4 acc2a = __builtin_amdgcn_mfma_f32_16x16x32_bf16(hfrag, w2f[0], z, 0, 0, 0);
        f32x4 acc2b = __builtin_amdgcn_mfma_f32_16x16x32_bf16(hfrag, w2f[1], z, 0, 0, 0);

        // h2 = gelu(acc2+b2) -> bf16 LDS [entry-in-tile][hidden] (wave-private, in-order DS)
#pragma unroll
        for (int r = 0; r < 4; ++r) {
            int row = 4 * qd + r;
            tb[row * 40 + li]      = f2bf(gelu_tanh(acc2a[r] + b2A));
            tb[row * 40 + li + 16] = f2bf(gelu_tanh(acc2b[r] + b2B));
        }

        // layer 3: A-fragment via b128 read-back, mfma
        bf16x8 h2 = *(const bf16x8*)&tb[li * 40 + qd * 8];
        f32x4 acc3a = __builtin_amdgcn_mfma_f32_16x16x32_bf16(h2, w3f[0], z, 0, 0, 0);
        f32x4 acc3b = __builtin_amdgcn_mfma_f32_16x16x32_bf16(h2, w3f[1], z, 0, 0, 0);

        // epilogue: acc_c += w_e * f[j_e][c] * (kv_e[c] + b3[c])
#pragma unroll
        for (int r = 0; r < 4; ++r) {
            int el = base + 4 * qd + r;
            float w = (el < cnt) ? (inv2 + ((pks[r] & 0x80000000u) ? inv1 : 0.0f)) : 0.0f;
            accA = fmaf(w * fAv[r], acc3a[r] + b3A, accA);
            accB = fmaf(w * fBv[r], acc3b[r] + b3B, accB);
        }
    }

    // ---- reduce over quads (entries); channels already on lanes ----
    accA += __shfl_xor(accA, 16, 64);
    accA += __shfl_xor(accA, 32, 64);
    accB += __shfl_xor(accB, 16, 64);
    accB += __shfl_xor(accB, 32, 64);
    if (lane < 16) {
        sred[wid][li] = accA;
        sred[wid][li + 16] = accB;
    }
    __syncthreads();
    if (tid < C_) {
        float s = 0.0f;
#pragma unroll
        for (int w = 0; w < 8; ++w) s += sred[w][tid];
        out[(size_t)bi * C_ + tid] = s;
    }
}

extern "C" void kernel_launch(void* const* d_in, const int* in_sizes, int n_in,
                              void* d_out, int out_size, void* d_ws, size_t ws_size,
                              hipStream_t stream) {
    const float* x_coord = (const float*)d_in[0];
    const float* pndata  = (const float*)d_in[1];
    const float* lat     = (const float*)d_in[2];
    const float* W_lift  = (const float*)d_in[3];
    const float* b_lift  = (const float*)d_in[4];
    const float* kW1     = (const float*)d_in[5];
    const float* kb1     = (const float*)d_in[6];
    const float* kW2     = (const float*)d_in[7];
    const float* kb2     = (const float*)d_in[8];
    const float* kW3     = (const float*)d_in[9];
    const float* kb3     = (const float*)d_in[10];
    float* out = (float*)d_out;

    float* f = (float*)d_ws;   // B*N*C fp32 = 512 KB scratch
    lift_kernel<<<(B_ * N_ + 7) / 8, 256, 0, stream>>>(pndata, W_lift, b_lift, f);
    magno_mfma<<<B_ * NL_, 512, 0, stream>>>(
        x_coord, lat, kW1, kb1, kW2, kb2, kW3, kb3, f, out);
}

// Round 10
// 85.837 us; speedup vs baseline: 1.0742x; 1.0742x over previous
//
#include <hip/hip_runtime.h>

// Problem constants (from reference setup_inputs)
static constexpr int B_ = 2, N_ = 2048, NL_ = 512, IN_C_ = 16, C_ = 32, H_ = 32;
static constexpr float R1SQ = (float)(0.07 * 0.07);   // (RADIUS*1)^2
static constexpr float R2SQ = (float)(0.14 * 0.14);   // (RADIUS*2)^2

typedef __attribute__((ext_vector_type(8))) short bf16x8;  // 8 bf16 = 4 VGPRs
typedef __attribute__((ext_vector_type(4))) float f32x4;   // 4 fp32 acc

// jax.nn.gelu(approximate=True) via 0.5x(1+tanh(z)) = x*(1 - 1/(exp(2z)+1)),
// with log2e folded: exp(2z) = exp2(C1*x*(1+0.044715x^2)),
// C1 = 2*sqrt(2/pi)*log2(e). rcp (1 ulp) absorbed by bf16 rounding downstream.
__device__ __forceinline__ float gelu_tanh(float x) {
    float z2 = 2.3022082f * x * fmaf(0.044715f * x, x, 1.0f);
    float e = __builtin_amdgcn_exp2f(z2);
    float t = __builtin_amdgcn_rcpf(e + 1.0f);
    return x - x * t;
}

// fp32 -> bf16 bits, round-to-nearest-even (inputs finite)
__device__ __forceinline__ short f2bf(float x) {
    unsigned u = __float_as_uint(x);
    u += 0x7fffu + ((u >> 16) & 1u);
    return (short)(u >> 16);
}

// f = pndata @ W_lift + b_lift   (B*N rows of 16 -> 32)
__global__ __launch_bounds__(256)
void lift_kernel(const float* __restrict__ pnd,
                 const float* __restrict__ Wl, const float* __restrict__ bl,
                 float* __restrict__ f)
{
    __shared__ float sW[IN_C_ * C_];
    __shared__ float sb[C_];
    int tid = threadIdx.x;
    for (int idx = tid; idx < IN_C_ * C_; idx += 256) sW[idx] = Wl[idx];
    if (tid < C_) sb[tid] = bl[tid];
    __syncthreads();
    int c = tid & 31;
    int row = blockIdx.x * 8 + (tid >> 5);
    if (row >= B_ * N_) return;
    const float* p = pnd + (size_t)row * IN_C_;
    float s = sb[c];
#pragma unroll
    for (int m = 0; m < IN_C_; ++m) s = fmaf(p[m], sW[m * C_ + c], s);
    f[(size_t)row * C_ + c] = s;
}

// One block per (b, latent token i). 256 threads = 4 waves.
// Wave-private compaction; Pass B = one 16-entry M-tile per iteration
// (fine granularity -> minimal padding work), ZERO block barriers inside.
// [R9 post-mortem: 512-thr/8-wave variant regressed (VGPR cap + barrier
//  coupling); this 4-wave structure is the empirical optimum.]
__global__ __launch_bounds__(256)
void magno_mfma(const float* __restrict__ x_coord,   // (B,N,2)
                const float* __restrict__ lat,        // (NL,2)
                const float* __restrict__ kW1, const float* __restrict__ kb1,
                const float* __restrict__ kW2, const float* __restrict__ kb2,
                const float* __restrict__ kW3, const float* __restrict__ kb3,
                const float* __restrict__ f,          // (B,N,32) fp32
                float* __restrict__ out)              // (B,NL,32)
{
    __shared__ float sW23[2][H_ * H_];                  // staged kW2, kW3
    __shared__ float sR0[H_], sR1[H_], sA1[H_];
    __shared__ unsigned jlist[4][512];                  // per-wave segments
    __shared__ __align__(16) short strans[4][16 * 40];  // per-wave bf16 transpose, 16 rows, pitch 40
    __shared__ float sred[4][C_];
    __shared__ int scnt[4][2];                          // per-wave {n, c1}

    const int tid  = threadIdx.x;
    const int lane = tid & 63;
    const int wid  = tid >> 6;
    const int qd   = lane >> 4;    // quad 0..3
    const int li   = lane & 15;
    const int bi = blockIdx.x;
    const int b = bi >> 9, i = bi & (NL_ - 1);
    const float xq0 = lat[2 * i], xq1 = lat[2 * i + 1];

    // ---- stage W2/W3 coalesced (first use after barrier) ----
    for (int idx = tid; idx < H_ * H_; idx += 256) {
        sW23[0][idx] = kW2[idx];
        sW23[1][idx] = kW3[idx];
    }
    if (tid < H_) {
        sR0[tid] = kW1[tid];
        sR1[tid] = kW1[H_ + tid];
        sA1[tid] = fmaf(xq0, kW1[2 * H_ + tid], fmaf(xq1, kW1[3 * H_ + tid], kb1[tid]));
    }
    const float b2A = kb2[li], b2B = kb2[li + 16];
    const float b3A = kb3[li], b3B = kb3[li + 16];

    // ---- Pass A: wave-private ballot compaction over j in [512*wid, 512*(wid+1)) ----
    const float2* __restrict__ xc = (const float2*)(x_coord + (size_t)b * N_ * 2);
    const unsigned long long ltmask = (1ull << lane) - 1ull;
    float2 ys[8];
#pragma unroll
    for (int t = 0; t < 8; ++t) ys[t] = xc[512 * wid + 64 * t + lane];   // all in flight
    int cnt = 0, c1w = 0;
#pragma unroll
    for (int t = 0; t < 8; ++t) {
        float dy0 = ys[t].x - xq0, dy1 = ys[t].y - xq1;
        float d2 = dy0 * dy0 + dy1 * dy1;
        bool in2 = d2 <= R2SQ;
        bool in1 = d2 <= R1SQ;
        unsigned long long m2 = __ballot(in2);
        unsigned long long m1 = __ballot(in1);
        if (in2) {
            int pos = cnt + __popcll(m2 & ltmask);
            jlist[wid][pos] = (unsigned)(512 * wid + 64 * t + lane) | (in1 ? 0x80000000u : 0u);
        }
        cnt += __popcll(m2);   // wave-uniform
        c1w += __popcll(m1);
    }
    if (lane == 0) { scnt[wid][0] = cnt; scnt[wid][1] = c1w; }
    __syncthreads();   // covers weight staging + scnt publication

    const int n  = scnt[0][0] + scnt[1][0] + scnt[2][0] + scnt[3][0];
    const int c1 = scnt[0][1] + scnt[1][1] + scnt[2][1] + scnt[3][1];
    const float inv2 = 1.0f / (float)(n  > 0 ? n  : 1);
    const float inv1 = 1.0f / (float)(c1 > 0 ? c1 : 1);

    // ---- B-fragments from LDS (verified 16x16x32 layout): B[k=qd*8+jj][n=li+16*nt] ----
    bf16x8 w2f[2], w3f[2];
#pragma unroll
    for (int nt = 0; nt < 2; ++nt) {
        int n0 = li + 16 * nt;
#pragma unroll
        for (int jj = 0; jj < 8; ++jj) {
            int k = qd * 8 + jj;
            w2f[nt][jj] = f2bf(sW23[0][k * H_ + n0]);
            w3f[nt][jj] = f2bf(sW23[1][k * H_ + n0]);
        }
    }

    // layer-1 weight slices for this lane's k-range
    float r0v[8], r1v[8], a1v[8];
#pragma unroll
    for (int jj = 0; jj < 8; ++jj) {
        int k = qd * 8 + jj;
        r0v[jj] = sR0[k]; r1v[jj] = sR1[k]; a1v[jj] = sA1[k];
    }

    short* tb = &strans[wid][0];
    const unsigned* __restrict__ jl = &jlist[wid][0];
    const float* __restrict__ fbase = f + (size_t)b * N_ * C_;

    float accA = 0.0f, accB = 0.0f;   // channels li and li+16

    // ---- Pass B: one 16-entry tile per iteration, wave-private, no block barriers ----
    for (int base = 0; base < cnt; base += 16) {
        // f prefetch for epilogue entries el = base + 4*qd + r (hidden under MLP)
        unsigned pks[4];
        float fAv[4], fBv[4];
#pragma unroll
        for (int r = 0; r < 4; ++r) {
            int el = base + 4 * qd + r;
            pks[r] = jl[el & 511];               // safe index; w=0 masks padding
            int j = (int)(pks[r] & (unsigned)(N_ - 1));
            const float* fr = fbase + (size_t)j * C_;
            fAv[r] = fr[li];
            fBv[r] = fr[li + 16];
        }

        // layer 1 directly in A-fragment layout: entry m = base + li
        int jm = (int)(jl[(base + li) & 511] & (unsigned)(N_ - 1));
        float2 y = xc[jm];   // L1/L2-warm (Pass A read all of xc)
        bf16x8 hfrag;
#pragma unroll
        for (int jj = 0; jj < 8; ++jj)
            hfrag[jj] = f2bf(gelu_tanh(fmaf(y.x, r0v[jj], fmaf(y.y, r1v[jj], a1v[jj]))));

        // layer 2 mfma
        f32x4 z = {0.f, 0.f, 0.f, 0.f};
        f32x4 acc2a = __builtin_amdgcn_mfma_f32_16x16x32_bf16(hfrag, w2f[0], z, 0, 0, 0);
        f32x4 acc2b = __builtin_amdgcn_mfma_f32_16x16x32_bf16(hfrag, w2f[1], z, 0, 0, 0);

        // h2 = gelu(acc2+b2) -> bf16 LDS [entry-in-tile][hidden] (wave-private, in-order DS)
#pragma unroll
        for (int r = 0; r < 4; ++r) {
            int row = 4 * qd + r;
            tb[row * 40 + li]      = f2bf(gelu_tanh(acc2a[r] + b2A));
            tb[row * 40 + li + 16] = f2bf(gelu_tanh(acc2b[r] + b2B));
        }

        // layer 3: A-fragment via b128 read-back, mfma
        bf16x8 h2 = *(const bf16x8*)&tb[li * 40 + qd * 8];
        f32x4 acc3a = __builtin_amdgcn_mfma_f32_16x16x32_bf16(h2, w3f[0], z, 0, 0, 0);
        f32x4 acc3b = __builtin_amdgcn_mfma_f32_16x16x32_bf16(h2, w3f[1], z, 0, 0, 0);

        // epilogue: acc_c += w_e * f[j_e][c] * (kv_e[c] + b3[c])
        // D layout: row(entry-in-tile) = 4*qd + r, col(channel) = li (+16)
#pragma unroll
        for (int r = 0; r < 4; ++r) {
            int el = base + 4 * qd + r;
            float w = (el < cnt) ? (inv2 + ((pks[r] & 0x80000000u) ? inv1 : 0.0f)) : 0.0f;
            accA = fmaf(w * fAv[r], acc3a[r] + b3A, accA);
            accB = fmaf(w * fBv[r], acc3b[r] + b3B, accB);
        }
    }

    // ---- reduce over quads (entries); channels already on lanes ----
    accA += __shfl_xor(accA, 16, 64);
    accA += __shfl_xor(accA, 32, 64);
    accB += __shfl_xor(accB, 16, 64);
    accB += __shfl_xor(accB, 32, 64);
    if (lane < 16) {
        sred[wid][li] = accA;
        sred[wid][li + 16] = accB;
    }
    __syncthreads();
    if (tid < C_)
        out[(size_t)bi * C_ + tid] = (sred[0][tid] + sred[1][tid]) + (sred[2][tid] + sred[3][tid]);
}

extern "C" void kernel_launch(void* const* d_in, const int* in_sizes, int n_in,
                              void* d_out, int out_size, void* d_ws, size_t ws_size,
                              hipStream_t stream) {
    const float* x_coord = (const float*)d_in[0];
    const float* pndata  = (const float*)d_in[1];
    const float* lat     = (const float*)d_in[2];
    const float* W_lift  = (const float*)d_in[3];
    const float* b_lift  = (const float*)d_in[4];
    const float* kW1     = (const float*)d_in[5];
    const float* kb1     = (const float*)d_in[6];
    const float* kW2     = (const float*)d_in[7];
    const float* kb2     = (const float*)d_in[8];
    const float* kW3     = (const float*)d_in[9];
    const float* kb3     = (const float*)d_in[10];
    float* out = (float*)d_out;

    float* f = (float*)d_ws;   // B*N*C fp32 = 512 KB scratch
    lift_kernel<<<(B_ * N_ + 7) / 8, 256, 0, stream>>>(pndata, W_lift, b_lift, f);
    magno_mfma<<<B_ * NL_, 256, 0, stream>>>(
        x_coord, lat, kW1, kb1, kW2, kb2, kW3, kb3, f, out);
}